// Round 4
// baseline (22.332 us; speedup 1.0000x reference)
//
#include <hip/hip_runtime.h>
#include <hip/hip_bf16.h>

// MedianPool2d: 3x3 median, stride 1, reflect pad 1.
// x: [16, 3, 512, 512] fp32 -> out same shape fp32.
// Wave-as-row: each wave owns a 512-wide stripe; lane l holds 8 consecutive
// floats (2x float4). Horizontal neighbors via __shfl (no scalar gathers).
// 8 output rows per thread, rolling 3-row min3/med3/max3 window.
// median9 = med3( max3(row-mins), med3(row-meds), min3(row-maxes) ).

__global__ __launch_bounds__(256) void median_pool_3x3_row(
    const float* __restrict__ x, float* __restrict__ out) {
    constexpr int H = 512;
    constexpr int W = 512;
    constexpr int TH = 8;   // output rows per thread

    // XCD-aware bijective swizzle: 768 blocks = 8 XCDs x 96.
    int b    = blockIdx.x;
    int wb   = (b & 7) * 96 + (b >> 3);
    int wave = threadIdx.x >> 6;
    int lane = threadIdx.x & 63;

    int stripe = wb * 4 + wave;      // 0..3071 (8-row stripes)
    int sh     = stripe & 63;        // stripe within image (512/8 = 64)
    int img    = stripe >> 6;        // n*c image index (0..47)

    int h0 = sh * TH;
    int w0 = lane * 8;
    const float* base = x + (size_t)img * (H * W);

    // rolling per-row horizontal stats: slot = input_row % 3
    float slo[3][8], smd[3][8], shi[3][8];

#define LOADROW(K, SLOT)                                                      \
    {                                                                         \
        int h_ = h0 - 1 + (K);                                                \
        h_ = (h_ < 0) ? 1 : ((h_ >= H) ? (2 * H - 2 - h_) : h_);              \
        const float* p_ = base + (size_t)h_ * W + w0;                         \
        float4 A = *reinterpret_cast<const float4*>(p_);                      \
        float4 B = *reinterpret_cast<const float4*>(p_ + 4);                  \
        float vm1 = __shfl_up(B.w, 1);                                        \
        vm1 = (lane == 0) ? A.y : vm1;    /* reflect: x[-1] = x[1] */         \
        float v8 = __shfl_down(A.x, 1);                                       \
        v8 = (lane == 63) ? B.z : v8;     /* reflect: x[512] = x[510] */      \
        float v_[10] = {vm1, A.x, A.y, A.z, A.w, B.x, B.y, B.z, B.w, v8};     \
        _Pragma("unroll")                                                     \
        for (int j = 0; j < 8; ++j) {                                         \
            slo[SLOT][j] = fminf(fminf(v_[j], v_[j + 1]), v_[j + 2]);         \
            smd[SLOT][j] = __builtin_amdgcn_fmed3f(v_[j], v_[j + 1], v_[j + 2]); \
            shi[SLOT][j] = fmaxf(fmaxf(v_[j], v_[j + 1]), v_[j + 2]);         \
        }                                                                     \
    }

    LOADROW(0, 0);
    LOADROW(1, 1);

    float* op = out + (size_t)(img * H + h0) * W + w0;

    #pragma unroll
    for (int r = 0; r < TH; ++r) {
        LOADROW(r + 2, (r + 2) % 3);
        const int s0 = r % 3, s1 = (r + 1) % 3, s2 = (r + 2) % 3;
        float o[8];
        #pragma unroll
        for (int j = 0; j < 8; ++j) {
            float mx = fmaxf(fmaxf(slo[s0][j], slo[s1][j]), slo[s2][j]);
            float md = __builtin_amdgcn_fmed3f(smd[s0][j], smd[s1][j], smd[s2][j]);
            float mn = fminf(fminf(shi[s0][j], shi[s1][j]), shi[s2][j]);
            o[j] = __builtin_amdgcn_fmed3f(mx, md, mn);
        }
        *reinterpret_cast<float4*>(op)     = make_float4(o[0], o[1], o[2], o[3]);
        *reinterpret_cast<float4*>(op + 4) = make_float4(o[4], o[5], o[6], o[7]);
        op += W;
    }
#undef LOADROW
}

extern "C" void kernel_launch(void* const* d_in, const int* in_sizes, int n_in,
                              void* d_out, int out_size, void* d_ws, size_t ws_size,
                              hipStream_t stream) {
    const float* x = (const float*)d_in[0];
    float* out = (float*)d_out;
    // 16*3*512*512 px / (64 px per thread) = 196608 threads = 768 blocks
    int blocks = in_sizes[0] / 64 / 256;
    median_pool_3x3_row<<<blocks, 256, 0, stream>>>(x, out);
}

// Round 6
// 20.741 us; speedup vs baseline: 1.0767x; 1.0767x over previous
//
#include <hip/hip_runtime.h>
#include <hip/hip_bf16.h>

// MedianPool2d: 3x3 median, stride 1, reflect pad 1.
// x: [16, 3, 512, 512] fp32 -> out same shape fp32.
// One thread computes a 16x4 output tile (float4 loads, 18 input rows,
// rolling 3-row stats window). Nontemporal stores keep the output stream
// from evicting halo rows out of L2. XCD-bijective block swizzle.
// median9 = med3( max3(row-mins), med3(row-meds), min3(row-maxes) ).

typedef float f32x4 __attribute__((ext_vector_type(4)));

__global__ __launch_bounds__(256) void median_pool_3x3_t16x4(
    const float* __restrict__ x, float* __restrict__ out) {
    constexpr int H = 512;
    constexpr int W = 512;
    constexpr int TH = 16;                // output rows per thread

    // XCD-aware bijective swizzle: 768 blocks = 8 XCDs x 96.
    int b   = blockIdx.x;
    int wb  = (b & 7) * 96 + (b >> 3);
    int idx = wb * 256 + threadIdx.x;

    int twq = idx & 127;                  // w-tile (128 per row)
    int t   = idx >> 7;
    int th  = t & 31;                     // h-tile (32 per image)
    int img = t >> 5;                     // n*c image (0..47)

    int h0 = th * TH;
    int w0 = twq * 4;
    const float* base = x + (size_t)img * (H * W);

    int wl = (w0 == 0)     ? 1     : w0 - 1;   // reflect left
    int wr = (w0 + 4 == W) ? W - 2 : w0 + 4;   // reflect right

    // rolling per-row horizontal stats: slot = input_row % 3
    float slo[3][4], smd[3][4], shi[3][4];

#define LOADROW(K, SLOT)                                                     \
    {                                                                        \
        int h_ = h0 - 1 + (K);                                               \
        h_ = (h_ < 0) ? 1 : ((h_ >= H) ? (2 * H - 2 - h_) : h_);             \
        const float* p_ = base + (size_t)h_ * W;                             \
        f32x4 v_ = *reinterpret_cast<const f32x4*>(p_ + w0);                 \
        float a0 = p_[wl], a1 = v_.x, a2 = v_.y, a3 = v_.z, a4 = v_.w,       \
              a5 = p_[wr];                                                   \
        slo[SLOT][0] = fminf(fminf(a0, a1), a2);                             \
        slo[SLOT][1] = fminf(fminf(a1, a2), a3);                             \
        slo[SLOT][2] = fminf(fminf(a2, a3), a4);                             \
        slo[SLOT][3] = fminf(fminf(a3, a4), a5);                             \
        smd[SLOT][0] = __builtin_amdgcn_fmed3f(a0, a1, a2);                  \
        smd[SLOT][1] = __builtin_amdgcn_fmed3f(a1, a2, a3);                  \
        smd[SLOT][2] = __builtin_amdgcn_fmed3f(a2, a3, a4);                  \
        smd[SLOT][3] = __builtin_amdgcn_fmed3f(a3, a4, a5);                  \
        shi[SLOT][0] = fmaxf(fmaxf(a0, a1), a2);                             \
        shi[SLOT][1] = fmaxf(fmaxf(a1, a2), a3);                             \
        shi[SLOT][2] = fmaxf(fmaxf(a2, a3), a4);                             \
        shi[SLOT][3] = fmaxf(fmaxf(a3, a4), a5);                             \
    }

    LOADROW(0, 0);
    LOADROW(1, 1);

    float* op = out + (size_t)(img * H + h0) * W + w0;

    #pragma unroll
    for (int r = 0; r < TH; ++r) {
        LOADROW(r + 2, (r + 2) % 3);
        const int s0 = r % 3, s1 = (r + 1) % 3, s2 = (r + 2) % 3;
        float o[4];
        #pragma unroll
        for (int j = 0; j < 4; ++j) {
            float mx = fmaxf(fmaxf(slo[s0][j], slo[s1][j]), slo[s2][j]);
            float md = __builtin_amdgcn_fmed3f(smd[s0][j], smd[s1][j], smd[s2][j]);
            float mn = fminf(fminf(shi[s0][j], shi[s1][j]), shi[s2][j]);
            o[j] = __builtin_amdgcn_fmed3f(mx, md, mn);
        }
        f32x4 ov = {o[0], o[1], o[2], o[3]};
        __builtin_nontemporal_store(ov,
            reinterpret_cast<f32x4*>(op + (size_t)r * W));
    }
#undef LOADROW
}

extern "C" void kernel_launch(void* const* d_in, const int* in_sizes, int n_in,
                              void* d_out, int out_size, void* d_ws, size_t ws_size,
                              hipStream_t stream) {
    const float* x = (const float*)d_in[0];
    float* out = (float*)d_out;
    int total_threads = in_sizes[0] / 64;   // 16x4 px per thread -> 196608
    int blocks = total_threads / 256;       // 768, exact (divisible by 8)
    median_pool_3x3_t16x4<<<blocks, 256, 0, stream>>>(x, out);
}